// Round 11
// baseline (195.963 us; speedup 1.0000x reference)
//
#include <hip/hip_runtime.h>

#define N_NODES 4096
#define F_IN    512
#define NH1     8
#define F1      64   // NH1*ND1
#define C2      16
#define MAXDEG  128  // Binomial(4095,0.005): mean 20.5, max ~50; 128 unreachable

__device__ __forceinline__ float wave_max(float v) {
    for (int o = 32; o >= 1; o >>= 1) v = fmaxf(v, __shfl_xor(v, o, 64));
    return v;
}
__device__ __forceinline__ float wave_sum(float v) {
    for (int o = 32; o >= 1; o >>= 1) v += __shfl_xor(v, o, 64);
    return v;
}

// ---------------------------------------------------------------------------
// CSR build, one BLOCK (256 threads) per row. Thread t owns a contiguous
// 1-4-uint4 slice with perfectly coalesced independent loads (p[t+i*256]) --
// 64x the load concurrency of the R10 wave-per-row version (which measured
// 808 GB/s, latency-bound). Per-block 16KB width detect (offset-histogram
// logic validated R1-R10; adj[0][0]=1 self-loop guarantees content; >=20
// expected hits at w=4 -> misclassification ~1e-12). Compaction order is
// arbitrary (validated since R1: softmax/gather are order-invariant).
// ---------------------------------------------------------------------------
__global__ __launch_bounds__(256) void build_csr_kernel(
        const unsigned char* __restrict__ adj,
        unsigned short* __restrict__ neigh, int* __restrict__ deg) {
    __shared__ unsigned int dcnts[5];
    __shared__ int dwf;
    __shared__ int cnt;
    const int t = threadIdx.x;
    const int row = blockIdx.x;

    if (t < 4) dcnts[t] = 0u;
    if (t == 0) { dcnts[4] = 0u; cnt = 0; }
    __syncthreads();

    // ---- width detect on first 16KB (same data every block; L2-broadcast) ----
    {
        unsigned int c0 = 0, c1 = 0, c2 = 0, c3 = 0, m = 0;
        const uint4* dp = (const uint4*)adj;
        #pragma unroll
        for (int i = 0; i < 4; ++i) {
            uint4 v = dp[t + i * 256];
            unsigned int wd[4] = {v.x, v.y, v.z, v.w};
            #pragma unroll
            for (int q = 0; q < 4; ++q) {
                unsigned int b0 = wd[q] & 0xffu, b1 = (wd[q] >> 8) & 0xffu;
                unsigned int b2 = (wd[q] >> 16) & 0xffu, b3 = wd[q] >> 24;
                if (b0) { c0++; m = m > b0 ? m : b0; }
                if (b1) { c1++; m = m > b1 ? m : b1; }
                if (b2) { c2++; m = m > b2 ? m : b2; }
                if (b3) { c3++; m = m > b3 ? m : b3; }
            }
        }
        atomicAdd(&dcnts[0], c0); atomicAdd(&dcnts[1], c1);
        atomicAdd(&dcnts[2], c2); atomicAdd(&dcnts[3], c3);
        atomicMax(&dcnts[4], m);
    }
    __syncthreads();
    if (t == 0) {
        int ww;
        if (dcnts[1] + dcnts[2] + dcnts[3] == 0u)   ww = 4;  // int32 {0,1}
        else if (dcnts[0] == 0u && dcnts[1] == 0u)  ww = 4;  // fp32
        else if (dcnts[0] == 0u && dcnts[2] == 0u)  ww = 2;  // f16
        else if (dcnts[4] <= 1u)                     ww = 1;  // bool/u8
        else                                         ww = 2;  // bf16
        dwf = ww;
    }
    __syncthreads();
    const int w = dwf;

    // ---- scan: thread t covers contiguous entry slices; bit-test logic is
    //      the R3..R10-validated per-word scan, re-based per thread ----
    unsigned short* outp = neigh + (size_t)row * MAXDEG;
    if (w == 1) {
        const uint4* p = (const uint4*)(adj + (size_t)row * N_NODES);
        uint4 v = p[t];                       // 16 entries/thread
        if (v.x | v.y | v.z | v.w) {
            unsigned int wd[4] = {v.x, v.y, v.z, v.w};
            int base = t * 16;
            for (int q = 0; q < 4; ++q) {
                unsigned int word = wd[q];
                for (int bb = 0; bb < 4; ++bb) {
                    if ((word >> (8 * bb)) & 0xffu) {
                        int pos = atomicAdd(&cnt, 1);
                        if (pos < MAXDEG) outp[pos] = (unsigned short)(base + q * 4 + bb);
                    }
                }
            }
        }
    } else if (w == 2) {
        const uint4* p = (const uint4*)(adj + (size_t)row * N_NODES * 2);
        uint4 v[2];
        #pragma unroll
        for (int i = 0; i < 2; ++i) v[i] = p[t + i * 256];   // coalesced
        #pragma unroll
        for (int i = 0; i < 2; ++i) {
            if ((v[i].x | v[i].y | v[i].z | v[i].w) == 0u) continue;
            unsigned int wd[4] = {v[i].x, v[i].y, v[i].z, v[i].w};
            int base = (t + i * 256) * 8;
            for (int q = 0; q < 4; ++q) {
                unsigned int word = wd[q];
                if (word & 0xffffu) {
                    int pos = atomicAdd(&cnt, 1);
                    if (pos < MAXDEG) outp[pos] = (unsigned short)(base + q * 2);
                }
                if (word >> 16) {
                    int pos = atomicAdd(&cnt, 1);
                    if (pos < MAXDEG) outp[pos] = (unsigned short)(base + q * 2 + 1);
                }
            }
        }
    } else {
        const uint4* p = (const uint4*)(adj + (size_t)row * N_NODES * 4);
        uint4 v[4];
        #pragma unroll
        for (int i = 0; i < 4; ++i) v[i] = p[t + i * 256];   // coalesced
        #pragma unroll
        for (int i = 0; i < 4; ++i) {
            if ((v[i].x | v[i].y | v[i].z | v[i].w) == 0u) continue;
            unsigned int wd[4] = {v[i].x, v[i].y, v[i].z, v[i].w};
            int base = (t + i * 256) * 4;
            for (int q = 0; q < 4; ++q) {
                if (wd[q]) {
                    int pos = atomicAdd(&cnt, 1);
                    if (pos < MAXDEG) outp[pos] = (unsigned short)(base + q);
                }
            }
        }
    }
    __syncthreads();
    if (t == 0) deg[row] = min(cnt, MAXDEG);
}

// ---------------------------------------------------------------------------
// GEMM1 + fused es/ed. R7/R10 verbatim (validated). 4 rows/block, W1 staged
// in 64-k LDS tiles.
// ---------------------------------------------------------------------------
__global__ __launch_bounds__(256) void gemm1_kernel(
        const float* __restrict__ x, const float* __restrict__ W1,
        const float* __restrict__ asrc, const float* __restrict__ adst,
        float* __restrict__ h1, float* __restrict__ es, float* __restrict__ ed) {
    __shared__ float xs[4 * F_IN];   // 8 KB
    __shared__ float wt[64 * 64];    // 16 KB
    const int t = threadIdx.x;
    const int row0 = blockIdx.x * 4;
    const float4* src = (const float4*)(x + (size_t)row0 * F_IN);
    float4* dst = (float4*)xs;
    for (int i = t; i < 4 * F_IN / 4; i += 256) dst[i] = src[i];
    const int c = t & 63;
    const int r = t >> 6;
    const float4* w1v = (const float4*)W1;
    float4* wtv = (float4*)wt;
    float a = 0.f;
    for (int k0 = 0; k0 < F_IN; k0 += 64) {
        __syncthreads();   // previous tile fully consumed (also covers xs stage)
        #pragma unroll
        for (int i = 0; i < 4; ++i)
            wtv[t + i * 256] = w1v[k0 * 16 + t + i * 256];  // 4096 floats coalesced
        __syncthreads();
        const float4* xr = (const float4*)&xs[r * F_IN + k0];
        #pragma unroll
        for (int kk = 0; kk < 64; kk += 4) {
            float4 xv = xr[kk >> 2];
            float w0 = wt[(kk + 0) * 64 + c];
            float w1 = wt[(kk + 1) * 64 + c];
            float w2 = wt[(kk + 2) * 64 + c];
            float w3 = wt[(kk + 3) * 64 + c];
            a += xv.x * w0 + xv.y * w1 + xv.z * w2 + xv.w * w3;
        }
    }
    const int n = row0 + r;
    h1[(size_t)n * F1 + c] = a;
    float s = a * asrc[c];
    float d = a * adst[c];
    s += __shfl_xor(s, 1); s += __shfl_xor(s, 2); s += __shfl_xor(s, 4);
    d += __shfl_xor(d, 1); d += __shfl_xor(d, 2); d += __shfl_xor(d, 4);
    if ((c & 7) == 0) {
        es[n * NH1 + (c >> 3)] = s;
        ed[n * NH1 + (c >> 3)] = d;
    }
}

// ---------------------------------------------------------------------------
// Attention layer 1 + ELU + fused gemm2/scores2. R7/R10 verbatim (validated).
// ---------------------------------------------------------------------------
__global__ __launch_bounds__(64) void attn1_kernel(
        const unsigned short* __restrict__ neigh, const int* __restrict__ deg,
        const float* __restrict__ h1, const float* __restrict__ es,
        const float* __restrict__ ed, const float* __restrict__ W2,
        const float* __restrict__ a2s, const float* __restrict__ a2d,
        float* __restrict__ h2, float* __restrict__ es2, float* __restrict__ ed2) {
    __shared__ unsigned short list[MAXDEG];
    __shared__ float pbuf[64 * 9];   // [slot][head], stride 9 vs bank conflicts
    __shared__ float arow[64];
    const int i = blockIdx.x;
    const int l = threadIdx.x;
    const int K = deg[i];
    const unsigned short* lst = neigh + (size_t)i * MAXDEG;
    for (int j = l; j < MAXDEG; j += 64) list[j] = (j < K) ? lst[j] : (unsigned short)0;
    __syncthreads();

    float m[NH1], lsum[NH1], esi[NH1];
    for (int h = 0; h < NH1; ++h) { m[h] = -1e30f; lsum[h] = 0.f; esi[h] = es[i * NH1 + h]; }
    float acc = 0.f;
    const int hq = l >> 3;

    for (int t0 = 0; t0 < K; t0 += 64) {
        const int tc = min(64, K - t0);
        const bool valid = l < tc;
        const int j = valid ? (int)list[t0 + l] : 0;
        float s[NH1];
        for (int h = 0; h < NH1; ++h) {
            float v = esi[h] + ed[j * NH1 + h];
            v = (v >= 0.f) ? v : 0.2f * v;       // LeakyReLU(0.2)
            s[h] = valid ? v : -1e30f;
        }
        float alpha[NH1];
        for (int h = 0; h < NH1; ++h) {
            float tm = wave_max(s[h]);
            float mnew = fmaxf(m[h], tm);
            float p = valid ? __expf(s[h] - mnew) : 0.f;  // lane u>=tc stores 0
            float ts = wave_sum(p);
            alpha[h] = __expf(m[h] - mnew);
            lsum[h] = lsum[h] * alpha[h] + ts;
            m[h] = mnew;
            pbuf[l * 9 + h] = p;
        }
        acc *= alpha[hq];
        __syncthreads();
        const int tcPad = (tc + 7) & ~7;
        for (int u = 0; u < tcPad; u += 8) {
            #pragma unroll
            for (int v = 0; v < 8; ++v) {
                int jn = (int)list[t0 + u + v];
                acc += pbuf[(u + v) * 9 + hq] * h1[(size_t)jn * F1 + l];
            }
        }
        __syncthreads();
    }
    float o = acc / lsum[hq];
    float a1v = (o > 0.f) ? o : (__expf(o) - 1.f);  // ELU

    // ---- fused gemm2 + scores2 epilogue (row-local; validated R7/R10) ----
    arow[l] = a1v;
    __syncthreads();
    const int cc = l & 15;
    const int kg = l >> 4;        // 0..3, 16-k slice each
    float hacc = 0.f;
    #pragma unroll
    for (int k = 0; k < 16; ++k)
        hacc += arow[kg * 16 + k] * W2[(kg * 16 + k) * C2 + cc];
    hacc += __shfl_xor(hacc, 16);
    hacc += __shfl_xor(hacc, 32);  // all lanes: h2[i][cc]
    if (l < C2) h2[(size_t)i * C2 + l] = hacc;
    float s2 = hacc * a2s[cc];
    float d2 = hacc * a2d[cc];
    s2 += __shfl_xor(s2, 1); s2 += __shfl_xor(s2, 2);
    s2 += __shfl_xor(s2, 4); s2 += __shfl_xor(s2, 8);
    d2 += __shfl_xor(d2, 1); d2 += __shfl_xor(d2, 2);
    d2 += __shfl_xor(d2, 4); d2 += __shfl_xor(d2, 8);
    if (l == 0) { es2[i] = s2; ed2[i] = d2; }
}

// ---------------------------------------------------------------------------
// Attention layer 2. R6/R10 verbatim (validated).
// ---------------------------------------------------------------------------
__global__ __launch_bounds__(64) void attn2_kernel(
        const unsigned short* __restrict__ neigh, const int* __restrict__ deg,
        const float* __restrict__ h2, const float* __restrict__ es2,
        const float* __restrict__ ed2, float* __restrict__ out) {
    __shared__ unsigned short list[MAXDEG];
    __shared__ float pbuf[64];
    const int i = blockIdx.x;
    const int l = threadIdx.x;
    const int K = deg[i];
    const int c = l & 15;
    const int g = l >> 4;
    const unsigned short* lst = neigh + (size_t)i * MAXDEG;
    for (int j = l; j < MAXDEG; j += 64) list[j] = (j < K) ? lst[j] : (unsigned short)0;
    __syncthreads();

    float m = -1e30f, lsum = 0.f, acc = 0.f;
    const float esi = es2[i];
    for (int t0 = 0; t0 < K; t0 += 64) {
        const int tc = min(64, K - t0);
        const bool valid = l < tc;
        const int j = valid ? (int)list[t0 + l] : 0;
        float v = esi + ed2[j];
        v = (v >= 0.f) ? v : 0.2f * v;
        float s = valid ? v : -1e30f;
        float tm = wave_max(s);
        float mnew = fmaxf(m, tm);
        float p = valid ? __expf(s - mnew) : 0.f;   // lane u>=tc stores 0
        float ts = wave_sum(p);
        float alpha = __expf(m - mnew);
        lsum = lsum * alpha + ts;
        m = mnew;
        pbuf[l] = p;
        acc *= alpha;                                // linear in partials
        __syncthreads();
        const int tcPad = (tc + 3) & ~3;
        for (int u = g; u < tcPad; u += 4) {
            int jn = (int)list[t0 + u];
            acc += pbuf[u] * h2[(size_t)jn * C2 + c];
        }
        __syncthreads();
    }
    acc += __shfl_xor(acc, 16);
    acc += __shfl_xor(acc, 32);
    if (l < C2) out[(size_t)i * C2 + l] = acc / lsum;
}

extern "C" void kernel_launch(void* const* d_in, const int* in_sizes, int n_in,
                              void* d_out, int out_size, void* d_ws, size_t ws_size,
                              hipStream_t stream) {
    const float* x           = (const float*)d_in[0];
    const unsigned char* adj = (const unsigned char*)d_in[1];
    const float* W1          = (const float*)d_in[2];
    const float* a1src       = (const float*)d_in[3];
    const float* a1dst       = (const float*)d_in[4];
    const float* W2          = (const float*)d_in[5];
    const float* a2src       = (const float*)d_in[6];
    const float* a2dst       = (const float*)d_in[7];
    float* out = (float*)d_out;

    // workspace layout (~2.6 MB), all offsets 256B-aligned
    char* ws = (char*)d_ws;
    size_t off = 256;
    unsigned short* neigh = (unsigned short*)(ws + off);
    off += (size_t)N_NODES * MAXDEG * 2;          // 1 MB
    int* deg = (int*)(ws + off);                  off += (size_t)N_NODES * 4;
    float* h1 = (float*)(ws + off);               off += (size_t)N_NODES * F1 * 4;
    float* es1 = (float*)(ws + off);              off += (size_t)N_NODES * NH1 * 4;
    float* ed1 = (float*)(ws + off);              off += (size_t)N_NODES * NH1 * 4;
    float* h2 = (float*)(ws + off);               off += (size_t)N_NODES * C2 * 4;
    float* es2 = (float*)(ws + off);              off += (size_t)N_NODES * 4;
    float* ed2 = (float*)(ws + off);              off += (size_t)N_NODES * 4;

    hipLaunchKernelGGL(build_csr_kernel, dim3(N_NODES), dim3(256), 0, stream,
                       adj, neigh, deg);
    hipLaunchKernelGGL(gemm1_kernel, dim3(N_NODES / 4), dim3(256), 0, stream,
                       x, W1, a1src, a1dst, h1, es1, ed1);
    hipLaunchKernelGGL(attn1_kernel, dim3(N_NODES), dim3(64), 0, stream,
                       neigh, deg, h1, es1, ed1, W2, a2src, a2dst, h2, es2, ed2);
    hipLaunchKernelGGL(attn2_kernel, dim3(N_NODES), dim3(64), 0, stream,
                       neigh, deg, h2, es2, ed2, out);
}

// Round 12
// 160.597 us; speedup vs baseline: 1.2202x; 1.2202x over previous
//
#include <hip/hip_runtime.h>

#define N_NODES 4096
#define F_IN    512
#define NH1     8
#define F1      64   // NH1*ND1
#define C2      16
#define MAXDEG  128  // Binomial(4095,0.005): mean 20.5, max ~50; 128 unreachable

__device__ __forceinline__ float wave_max(float v) {
    for (int o = 32; o >= 1; o >>= 1) v = fmaxf(v, __shfl_xor(v, o, 64));
    return v;
}
__device__ __forceinline__ float wave_sum(float v) {
    for (int o = 32; o >= 1; o >>= 1) v += __shfl_xor(v, o, 64);
    return v;
}

// ---------------------------------------------------------------------------
// Detect adjacency element width (1/2/4 bytes). R1/R4/R6-validated verbatim.
// Runs ONCE (1 block) — R11 showed per-block detect costs ~20-40 µs in
// aggregate (LDS same-address atomic serialization x 4096 blocks).
// ---------------------------------------------------------------------------
__global__ void detect_width_kernel(const unsigned char* __restrict__ adj,
                                    int* __restrict__ flag) {
    __shared__ unsigned int cnts[4];
    __shared__ unsigned int mxv;
    int t = threadIdx.x;
    if (t < 4) cnts[t] = 0u;
    if (t == 0) mxv = 0u;
    __syncthreads();
    unsigned int c0 = 0, c1 = 0, c2 = 0, c3 = 0, m = 0;
    const unsigned int* p = (const unsigned int*)(adj) + t * 64;  // 256 B/thread
    for (int i = 0; i < 64; ++i) {
        unsigned int v = p[i];
        unsigned int b0 = v & 0xffu, b1 = (v >> 8) & 0xffu;
        unsigned int b2 = (v >> 16) & 0xffu, b3 = (v >> 24) & 0xffu;
        if (b0) { c0++; m = m > b0 ? m : b0; }
        if (b1) { c1++; m = m > b1 ? m : b1; }
        if (b2) { c2++; m = m > b2 ? m : b2; }
        if (b3) { c3++; m = m > b3 ? m : b3; }
    }
    atomicAdd(&cnts[0], c0); atomicAdd(&cnts[1], c1);
    atomicAdd(&cnts[2], c2); atomicAdd(&cnts[3], c3);
    atomicMax(&mxv, m);
    __syncthreads();
    if (t == 0) {
        int w;
        if (cnts[1] + cnts[2] + cnts[3] == 0u)      w = 4;  // int32 {0,1}
        else if (cnts[0] == 0u && cnts[1] == 0u)    w = 4;  // fp32 {0,1.0f}
        else if (cnts[0] == 0u && cnts[2] == 0u)    w = 2;  // f16 1.0 (odd bytes)
        else if (mxv <= 1u)                          w = 1;  // bool/uint8
        else                                         w = 2;  // bf16 1.0
        *flag = w;
    }
}

// ---------------------------------------------------------------------------
// CSR build, one BLOCK (256 threads) per row — R11-validated scan body, with
// the per-block detect REMOVED (reads flag). Thread t owns contiguous
// 1-4 uint4 with fully coalesced independent loads; ~41 low-contention LDS
// atomics per block. Compaction order arbitrary (validated since R1).
// ---------------------------------------------------------------------------
__global__ __launch_bounds__(256) void build_csr_kernel(
        const unsigned char* __restrict__ adj, const int* __restrict__ flag,
        unsigned short* __restrict__ neigh, int* __restrict__ deg) {
    __shared__ int cnt;
    const int t = threadIdx.x;
    const int row = blockIdx.x;
    if (t == 0) cnt = 0;
    __syncthreads();
    const int w = *flag;

    unsigned short* outp = neigh + (size_t)row * MAXDEG;
    if (w == 1) {
        const uint4* p = (const uint4*)(adj + (size_t)row * N_NODES);
        uint4 v = p[t];                       // 16 entries/thread
        if (v.x | v.y | v.z | v.w) {
            unsigned int wd[4] = {v.x, v.y, v.z, v.w};
            int base = t * 16;
            for (int q = 0; q < 4; ++q) {
                unsigned int word = wd[q];
                for (int bb = 0; bb < 4; ++bb) {
                    if ((word >> (8 * bb)) & 0xffu) {
                        int pos = atomicAdd(&cnt, 1);
                        if (pos < MAXDEG) outp[pos] = (unsigned short)(base + q * 4 + bb);
                    }
                }
            }
        }
    } else if (w == 2) {
        const uint4* p = (const uint4*)(adj + (size_t)row * N_NODES * 2);
        uint4 v[2];
        #pragma unroll
        for (int i = 0; i < 2; ++i) v[i] = p[t + i * 256];   // coalesced
        #pragma unroll
        for (int i = 0; i < 2; ++i) {
            if ((v[i].x | v[i].y | v[i].z | v[i].w) == 0u) continue;
            unsigned int wd[4] = {v[i].x, v[i].y, v[i].z, v[i].w};
            int base = (t + i * 256) * 8;
            for (int q = 0; q < 4; ++q) {
                unsigned int word = wd[q];
                if (word & 0xffffu) {
                    int pos = atomicAdd(&cnt, 1);
                    if (pos < MAXDEG) outp[pos] = (unsigned short)(base + q * 2);
                }
                if (word >> 16) {
                    int pos = atomicAdd(&cnt, 1);
                    if (pos < MAXDEG) outp[pos] = (unsigned short)(base + q * 2 + 1);
                }
            }
        }
    } else {
        const uint4* p = (const uint4*)(adj + (size_t)row * N_NODES * 4);
        uint4 v[4];
        #pragma unroll
        for (int i = 0; i < 4; ++i) v[i] = p[t + i * 256];   // coalesced
        #pragma unroll
        for (int i = 0; i < 4; ++i) {
            if ((v[i].x | v[i].y | v[i].z | v[i].w) == 0u) continue;
            unsigned int wd[4] = {v[i].x, v[i].y, v[i].z, v[i].w};
            int base = (t + i * 256) * 4;
            for (int q = 0; q < 4; ++q) {
                if (wd[q]) {
                    int pos = atomicAdd(&cnt, 1);
                    if (pos < MAXDEG) outp[pos] = (unsigned short)(base + q);
                }
            }
        }
    }
    __syncthreads();
    if (t == 0) deg[row] = min(cnt, MAXDEG);
}

// ---------------------------------------------------------------------------
// GEMM1 + fused es/ed. R7/R10 verbatim (validated). 4 rows/block, W1 staged
// in 64-k LDS tiles.
// ---------------------------------------------------------------------------
__global__ __launch_bounds__(256) void gemm1_kernel(
        const float* __restrict__ x, const float* __restrict__ W1,
        const float* __restrict__ asrc, const float* __restrict__ adst,
        float* __restrict__ h1, float* __restrict__ es, float* __restrict__ ed) {
    __shared__ float xs[4 * F_IN];   // 8 KB
    __shared__ float wt[64 * 64];    // 16 KB
    const int t = threadIdx.x;
    const int row0 = blockIdx.x * 4;
    const float4* src = (const float4*)(x + (size_t)row0 * F_IN);
    float4* dst = (float4*)xs;
    for (int i = t; i < 4 * F_IN / 4; i += 256) dst[i] = src[i];
    const int c = t & 63;
    const int r = t >> 6;
    const float4* w1v = (const float4*)W1;
    float4* wtv = (float4*)wt;
    float a = 0.f;
    for (int k0 = 0; k0 < F_IN; k0 += 64) {
        __syncthreads();   // previous tile fully consumed (also covers xs stage)
        #pragma unroll
        for (int i = 0; i < 4; ++i)
            wtv[t + i * 256] = w1v[k0 * 16 + t + i * 256];  // 4096 floats coalesced
        __syncthreads();
        const float4* xr = (const float4*)&xs[r * F_IN + k0];
        #pragma unroll
        for (int kk = 0; kk < 64; kk += 4) {
            float4 xv = xr[kk >> 2];
            float w0 = wt[(kk + 0) * 64 + c];
            float w1 = wt[(kk + 1) * 64 + c];
            float w2 = wt[(kk + 2) * 64 + c];
            float w3 = wt[(kk + 3) * 64 + c];
            a += xv.x * w0 + xv.y * w1 + xv.z * w2 + xv.w * w3;
        }
    }
    const int n = row0 + r;
    h1[(size_t)n * F1 + c] = a;
    float s = a * asrc[c];
    float d = a * adst[c];
    s += __shfl_xor(s, 1); s += __shfl_xor(s, 2); s += __shfl_xor(s, 4);
    d += __shfl_xor(d, 1); d += __shfl_xor(d, 2); d += __shfl_xor(d, 4);
    if ((c & 7) == 0) {
        es[n * NH1 + (c >> 3)] = s;
        ed[n * NH1 + (c >> 3)] = d;
    }
}

// ---------------------------------------------------------------------------
// Attention layer 1 + ELU + fused gemm2/scores2. R7/R10 verbatim (validated).
// ---------------------------------------------------------------------------
__global__ __launch_bounds__(64) void attn1_kernel(
        const unsigned short* __restrict__ neigh, const int* __restrict__ deg,
        const float* __restrict__ h1, const float* __restrict__ es,
        const float* __restrict__ ed, const float* __restrict__ W2,
        const float* __restrict__ a2s, const float* __restrict__ a2d,
        float* __restrict__ h2, float* __restrict__ es2, float* __restrict__ ed2) {
    __shared__ unsigned short list[MAXDEG];
    __shared__ float pbuf[64 * 9];   // [slot][head], stride 9 vs bank conflicts
    __shared__ float arow[64];
    const int i = blockIdx.x;
    const int l = threadIdx.x;
    const int K = deg[i];
    const unsigned short* lst = neigh + (size_t)i * MAXDEG;
    for (int j = l; j < MAXDEG; j += 64) list[j] = (j < K) ? lst[j] : (unsigned short)0;
    __syncthreads();

    float m[NH1], lsum[NH1], esi[NH1];
    for (int h = 0; h < NH1; ++h) { m[h] = -1e30f; lsum[h] = 0.f; esi[h] = es[i * NH1 + h]; }
    float acc = 0.f;
    const int hq = l >> 3;

    for (int t0 = 0; t0 < K; t0 += 64) {
        const int tc = min(64, K - t0);
        const bool valid = l < tc;
        const int j = valid ? (int)list[t0 + l] : 0;
        float s[NH1];
        for (int h = 0; h < NH1; ++h) {
            float v = esi[h] + ed[j * NH1 + h];
            v = (v >= 0.f) ? v : 0.2f * v;       // LeakyReLU(0.2)
            s[h] = valid ? v : -1e30f;
        }
        float alpha[NH1];
        for (int h = 0; h < NH1; ++h) {
            float tm = wave_max(s[h]);
            float mnew = fmaxf(m[h], tm);
            float p = valid ? __expf(s[h] - mnew) : 0.f;  // lane u>=tc stores 0
            float ts = wave_sum(p);
            alpha[h] = __expf(m[h] - mnew);
            lsum[h] = lsum[h] * alpha[h] + ts;
            m[h] = mnew;
            pbuf[l * 9 + h] = p;
        }
        acc *= alpha[hq];
        __syncthreads();
        const int tcPad = (tc + 7) & ~7;
        for (int u = 0; u < tcPad; u += 8) {
            #pragma unroll
            for (int v = 0; v < 8; ++v) {
                int jn = (int)list[t0 + u + v];
                acc += pbuf[(u + v) * 9 + hq] * h1[(size_t)jn * F1 + l];
            }
        }
        __syncthreads();
    }
    float o = acc / lsum[hq];
    float a1v = (o > 0.f) ? o : (__expf(o) - 1.f);  // ELU

    // ---- fused gemm2 + scores2 epilogue (row-local; validated R7/R10) ----
    arow[l] = a1v;
    __syncthreads();
    const int cc = l & 15;
    const int kg = l >> 4;        // 0..3, 16-k slice each
    float hacc = 0.f;
    #pragma unroll
    for (int k = 0; k < 16; ++k)
        hacc += arow[kg * 16 + k] * W2[(kg * 16 + k) * C2 + cc];
    hacc += __shfl_xor(hacc, 16);
    hacc += __shfl_xor(hacc, 32);  // all lanes: h2[i][cc]
    if (l < C2) h2[(size_t)i * C2 + l] = hacc;
    float s2 = hacc * a2s[cc];
    float d2 = hacc * a2d[cc];
    s2 += __shfl_xor(s2, 1); s2 += __shfl_xor(s2, 2);
    s2 += __shfl_xor(s2, 4); s2 += __shfl_xor(s2, 8);
    d2 += __shfl_xor(d2, 1); d2 += __shfl_xor(d2, 2);
    d2 += __shfl_xor(d2, 4); d2 += __shfl_xor(d2, 8);
    if (l == 0) { es2[i] = s2; ed2[i] = d2; }
}

// ---------------------------------------------------------------------------
// Attention layer 2. R6/R10 verbatim (validated).
// ---------------------------------------------------------------------------
__global__ __launch_bounds__(64) void attn2_kernel(
        const unsigned short* __restrict__ neigh, const int* __restrict__ deg,
        const float* __restrict__ h2, const float* __restrict__ es2,
        const float* __restrict__ ed2, float* __restrict__ out) {
    __shared__ unsigned short list[MAXDEG];
    __shared__ float pbuf[64];
    const int i = blockIdx.x;
    const int l = threadIdx.x;
    const int K = deg[i];
    const int c = l & 15;
    const int g = l >> 4;
    const unsigned short* lst = neigh + (size_t)i * MAXDEG;
    for (int j = l; j < MAXDEG; j += 64) list[j] = (j < K) ? lst[j] : (unsigned short)0;
    __syncthreads();

    float m = -1e30f, lsum = 0.f, acc = 0.f;
    const float esi = es2[i];
    for (int t0 = 0; t0 < K; t0 += 64) {
        const int tc = min(64, K - t0);
        const bool valid = l < tc;
        const int j = valid ? (int)list[t0 + l] : 0;
        float v = esi + ed2[j];
        v = (v >= 0.f) ? v : 0.2f * v;
        float s = valid ? v : -1e30f;
        float tm = wave_max(s);
        float mnew = fmaxf(m, tm);
        float p = valid ? __expf(s - mnew) : 0.f;   // lane u>=tc stores 0
        float ts = wave_sum(p);
        float alpha = __expf(m - mnew);
        lsum = lsum * alpha + ts;
        m = mnew;
        pbuf[l] = p;
        acc *= alpha;                                // linear in partials
        __syncthreads();
        const int tcPad = (tc + 3) & ~3;
        for (int u = g; u < tcPad; u += 4) {
            int jn = (int)list[t0 + u];
            acc += pbuf[u] * h2[(size_t)jn * C2 + c];
        }
        __syncthreads();
    }
    acc += __shfl_xor(acc, 16);
    acc += __shfl_xor(acc, 32);
    if (l < C2) out[(size_t)i * C2 + l] = acc / lsum;
}

extern "C" void kernel_launch(void* const* d_in, const int* in_sizes, int n_in,
                              void* d_out, int out_size, void* d_ws, size_t ws_size,
                              hipStream_t stream) {
    const float* x           = (const float*)d_in[0];
    const unsigned char* adj = (const unsigned char*)d_in[1];
    const float* W1          = (const float*)d_in[2];
    const float* a1src       = (const float*)d_in[3];
    const float* a1dst       = (const float*)d_in[4];
    const float* W2          = (const float*)d_in[5];
    const float* a2src       = (const float*)d_in[6];
    const float* a2dst       = (const float*)d_in[7];
    float* out = (float*)d_out;

    // workspace layout (~2.6 MB), all offsets 256B-aligned
    char* ws = (char*)d_ws;
    size_t off = 0;
    int* flag = (int*)(ws + off);                 off += 256;
    unsigned short* neigh = (unsigned short*)(ws + off);
    off += (size_t)N_NODES * MAXDEG * 2;          // 1 MB
    int* deg = (int*)(ws + off);                  off += (size_t)N_NODES * 4;
    float* h1 = (float*)(ws + off);               off += (size_t)N_NODES * F1 * 4;
    float* es1 = (float*)(ws + off);              off += (size_t)N_NODES * NH1 * 4;
    float* ed1 = (float*)(ws + off);              off += (size_t)N_NODES * NH1 * 4;
    float* h2 = (float*)(ws + off);               off += (size_t)N_NODES * C2 * 4;
    float* es2 = (float*)(ws + off);              off += (size_t)N_NODES * 4;
    float* ed2 = (float*)(ws + off);              off += (size_t)N_NODES * 4;

    hipLaunchKernelGGL(detect_width_kernel, dim3(1), dim3(256), 0, stream, adj, flag);
    hipLaunchKernelGGL(build_csr_kernel, dim3(N_NODES), dim3(256), 0, stream,
                       adj, flag, neigh, deg);
    hipLaunchKernelGGL(gemm1_kernel, dim3(N_NODES / 4), dim3(256), 0, stream,
                       x, W1, a1src, a1dst, h1, es1, ed1);
    hipLaunchKernelGGL(attn1_kernel, dim3(N_NODES), dim3(64), 0, stream,
                       neigh, deg, h1, es1, ed1, W2, a2src, a2dst, h2, es2, ed2);
    hipLaunchKernelGGL(attn2_kernel, dim3(N_NODES), dim3(64), 0, stream,
                       neigh, deg, h2, es2, ed2, out);
}

// Round 13
// 159.360 us; speedup vs baseline: 1.2297x; 1.0078x over previous
//
#include <hip/hip_runtime.h>

#define N_NODES 4096
#define F_IN    512
#define NH1     8
#define F1      64   // NH1*ND1
#define C2      16
#define MAXDEG  128  // Binomial(4095,0.005): mean 20.5, max ~50; 128 unreachable

__device__ __forceinline__ float wave_max(float v) {
    for (int o = 32; o >= 1; o >>= 1) v = fmaxf(v, __shfl_xor(v, o, 64));
    return v;
}
__device__ __forceinline__ float wave_sum(float v) {
    for (int o = 32; o >= 1; o >>= 1) v += __shfl_xor(v, o, 64);
    return v;
}

// ---------------------------------------------------------------------------
// Detect adjacency element width (1/2/4 bytes). R1/R4/R6/R12-validated
// verbatim. One block, runs once.
// ---------------------------------------------------------------------------
__global__ void detect_width_kernel(const unsigned char* __restrict__ adj,
                                    int* __restrict__ flag) {
    __shared__ unsigned int cnts[4];
    __shared__ unsigned int mxv;
    int t = threadIdx.x;
    if (t < 4) cnts[t] = 0u;
    if (t == 0) mxv = 0u;
    __syncthreads();
    unsigned int c0 = 0, c1 = 0, c2 = 0, c3 = 0, m = 0;
    const unsigned int* p = (const unsigned int*)(adj) + t * 64;  // 256 B/thread
    for (int i = 0; i < 64; ++i) {
        unsigned int v = p[i];
        unsigned int b0 = v & 0xffu, b1 = (v >> 8) & 0xffu;
        unsigned int b2 = (v >> 16) & 0xffu, b3 = (v >> 24) & 0xffu;
        if (b0) { c0++; m = m > b0 ? m : b0; }
        if (b1) { c1++; m = m > b1 ? m : b1; }
        if (b2) { c2++; m = m > b2 ? m : b2; }
        if (b3) { c3++; m = m > b3 ? m : b3; }
    }
    atomicAdd(&cnts[0], c0); atomicAdd(&cnts[1], c1);
    atomicAdd(&cnts[2], c2); atomicAdd(&cnts[3], c3);
    atomicMax(&mxv, m);
    __syncthreads();
    if (t == 0) {
        int w;
        if (cnts[1] + cnts[2] + cnts[3] == 0u)      w = 4;  // int32 {0,1}
        else if (cnts[0] == 0u && cnts[1] == 0u)    w = 4;  // fp32 {0,1.0f}
        else if (cnts[0] == 0u && cnts[2] == 0u)    w = 2;  // f16 1.0 (odd bytes)
        else if (mxv <= 1u)                          w = 1;  // bool/uint8
        else                                         w = 2;  // bf16 1.0
        *flag = w;
    }
}

// ---------------------------------------------------------------------------
// Fused front-end: blocks [0,4096) run the R12-validated CSR row scan;
// blocks [4096,5120) run the R10-validated gemm1 (+fused es/ed). The two are
// data-independent, so mixing them lets BW-bound csr and VALU/LDS-bound
// gemm1 overlap across CUs instead of serializing as two launches.
// ---------------------------------------------------------------------------
__global__ __launch_bounds__(256) void frontend_kernel(
        const unsigned char* __restrict__ adj, const int* __restrict__ flag,
        unsigned short* __restrict__ neigh, int* __restrict__ deg,
        const float* __restrict__ x, const float* __restrict__ W1,
        const float* __restrict__ asrc, const float* __restrict__ adst,
        float* __restrict__ h1, float* __restrict__ es, float* __restrict__ ed) {
    __shared__ __align__(16) char smem[24576];
    const int t = threadIdx.x;

    if (blockIdx.x < N_NODES) {
        // ---- CSR scan (R12-validated body) ----
        int* cnt = (int*)smem;
        const int row = blockIdx.x;
        if (t == 0) *cnt = 0;
        __syncthreads();
        const int w = *flag;
        unsigned short* outp = neigh + (size_t)row * MAXDEG;
        if (w == 1) {
            const uint4* p = (const uint4*)(adj + (size_t)row * N_NODES);
            uint4 v = p[t];                       // 16 entries/thread
            if (v.x | v.y | v.z | v.w) {
                unsigned int wd[4] = {v.x, v.y, v.z, v.w};
                int base = t * 16;
                for (int q = 0; q < 4; ++q) {
                    unsigned int word = wd[q];
                    for (int bb = 0; bb < 4; ++bb) {
                        if ((word >> (8 * bb)) & 0xffu) {
                            int pos = atomicAdd(cnt, 1);
                            if (pos < MAXDEG) outp[pos] = (unsigned short)(base + q * 4 + bb);
                        }
                    }
                }
            }
        } else if (w == 2) {
            const uint4* p = (const uint4*)(adj + (size_t)row * N_NODES * 2);
            uint4 v[2];
            #pragma unroll
            for (int i = 0; i < 2; ++i) v[i] = p[t + i * 256];   // coalesced
            #pragma unroll
            for (int i = 0; i < 2; ++i) {
                if ((v[i].x | v[i].y | v[i].z | v[i].w) == 0u) continue;
                unsigned int wd[4] = {v[i].x, v[i].y, v[i].z, v[i].w};
                int base = (t + i * 256) * 8;
                for (int q = 0; q < 4; ++q) {
                    unsigned int word = wd[q];
                    if (word & 0xffffu) {
                        int pos = atomicAdd(cnt, 1);
                        if (pos < MAXDEG) outp[pos] = (unsigned short)(base + q * 2);
                    }
                    if (word >> 16) {
                        int pos = atomicAdd(cnt, 1);
                        if (pos < MAXDEG) outp[pos] = (unsigned short)(base + q * 2 + 1);
                    }
                }
            }
        } else {
            const uint4* p = (const uint4*)(adj + (size_t)row * N_NODES * 4);
            uint4 v[4];
            #pragma unroll
            for (int i = 0; i < 4; ++i) v[i] = p[t + i * 256];   // coalesced
            #pragma unroll
            for (int i = 0; i < 4; ++i) {
                if ((v[i].x | v[i].y | v[i].z | v[i].w) == 0u) continue;
                unsigned int wd[4] = {v[i].x, v[i].y, v[i].z, v[i].w};
                int base = (t + i * 256) * 4;
                for (int q = 0; q < 4; ++q) {
                    if (wd[q]) {
                        int pos = atomicAdd(cnt, 1);
                        if (pos < MAXDEG) outp[pos] = (unsigned short)(base + q);
                    }
                }
            }
        }
        __syncthreads();
        if (t == 0) deg[row] = min(*cnt, MAXDEG);
    } else {
        // ---- GEMM1 + fused es/ed (R10-validated body; row re-based) ----
        float* xs = (float*)smem;            // 2048 floats, 8 KB
        float* wt = (float*)(smem + 8192);   // 4096 floats, 16 KB
        const int row0 = (blockIdx.x - N_NODES) * 4;
        const float4* src = (const float4*)(x + (size_t)row0 * F_IN);
        float4* dst = (float4*)xs;
        for (int i = t; i < 4 * F_IN / 4; i += 256) dst[i] = src[i];
        const int c = t & 63;
        const int r = t >> 6;
        const float4* w1v = (const float4*)W1;
        float4* wtv = (float4*)wt;
        float a = 0.f;
        for (int k0 = 0; k0 < F_IN; k0 += 64) {
            __syncthreads();   // previous tile consumed (also covers xs stage)
            #pragma unroll
            for (int i = 0; i < 4; ++i)
                wtv[t + i * 256] = w1v[k0 * 16 + t + i * 256];  // coalesced
            __syncthreads();
            const float4* xr = (const float4*)&xs[r * F_IN + k0];
            #pragma unroll
            for (int kk = 0; kk < 64; kk += 4) {
                float4 xv = xr[kk >> 2];
                float w0 = wt[(kk + 0) * 64 + c];
                float w1 = wt[(kk + 1) * 64 + c];
                float w2 = wt[(kk + 2) * 64 + c];
                float w3 = wt[(kk + 3) * 64 + c];
                a += xv.x * w0 + xv.y * w1 + xv.z * w2 + xv.w * w3;
            }
        }
        const int n = row0 + r;
        h1[(size_t)n * F1 + c] = a;
        float s = a * asrc[c];
        float d = a * adst[c];
        s += __shfl_xor(s, 1); s += __shfl_xor(s, 2); s += __shfl_xor(s, 4);
        d += __shfl_xor(d, 1); d += __shfl_xor(d, 2); d += __shfl_xor(d, 4);
        if ((c & 7) == 0) {
            es[n * NH1 + (c >> 3)] = s;
            ed[n * NH1 + (c >> 3)] = d;
        }
    }
}

// ---------------------------------------------------------------------------
// Attention layer 1 + ELU + fused gemm2/scores2. R9 mega-kernel phase D
// (validated end-to-end) as a standalone kernel: 4 waves/block, per-wave LDS
// slices, fixed 2-trip tile loop with uniform barriers. 1024 blocks ->
// full 32-wave/CU packing (vs 64-thread blocks' potential 16-wg/CU cap).
// ---------------------------------------------------------------------------
__global__ __launch_bounds__(256) void attn1_kernel(
        const unsigned short* __restrict__ neigh, const int* __restrict__ deg,
        const float* __restrict__ h1, const float* __restrict__ es,
        const float* __restrict__ ed, const float* __restrict__ W2,
        const float* __restrict__ a2s, const float* __restrict__ a2d,
        float* __restrict__ h2, float* __restrict__ es2, float* __restrict__ ed2) {
    __shared__ unsigned short listA[4 * MAXDEG];
    __shared__ float arowA[4 * 64];
    __shared__ float pbufA[4 * 576];
    const int t = threadIdx.x;
    const int wv = t >> 6;
    const int l = t & 63;
    const int i = blockIdx.x * 4 + wv;
    unsigned short* list = listA + wv * MAXDEG;
    float* arow = arowA + wv * 64;
    float* pw   = pbufA + wv * 576;
    const int hq = l >> 3;

    const int K = deg[i];
    const unsigned short* lst = neigh + (size_t)i * MAXDEG;
    for (int j = l; j < MAXDEG; j += 64) list[j] = (j < K) ? lst[j] : (unsigned short)0;
    __syncthreads();

    float m[NH1], lsum[NH1], esi[NH1];
    for (int h = 0; h < NH1; ++h) { m[h] = -1e30f; lsum[h] = 0.f; esi[h] = es[i * NH1 + h]; }
    float acc = 0.f;

    for (int t0 = 0; t0 < MAXDEG; t0 += 64) {    // fixed 2 trips
        const int tc = min(64, K - t0);
        if (tc > 0) {
            const bool valid = l < tc;
            const int j = valid ? (int)list[t0 + l] : 0;
            float s[NH1], alpha[NH1];
            for (int h = 0; h < NH1; ++h) {
                float v = esi[h] + ed[j * NH1 + h];
                v = (v >= 0.f) ? v : 0.2f * v;   // LeakyReLU(0.2)
                s[h] = valid ? v : -1e30f;
            }
            for (int h = 0; h < NH1; ++h) {
                float tm = wave_max(s[h]);
                float mnew = fmaxf(m[h], tm);
                float p = valid ? __expf(s[h] - mnew) : 0.f;
                float ts = wave_sum(p);
                alpha[h] = __expf(m[h] - mnew);
                lsum[h] = lsum[h] * alpha[h] + ts;
                m[h] = mnew;
                pw[l * 9 + h] = p;
            }
            acc *= alpha[hq];
        }
        __syncthreads();             // uniform
        if (tc > 0) {
            const int tcPad = (tc + 7) & ~7;
            for (int u = 0; u < tcPad; u += 8) {
                #pragma unroll
                for (int vv = 0; vv < 8; ++vv) {
                    int jn = (int)list[t0 + u + vv];
                    acc += pw[(u + vv) * 9 + hq] * h1[(size_t)jn * F1 + l];
                }
            }
        }
        __syncthreads();             // uniform
    }
    float o = acc / lsum[hq];
    float a1v = (o > 0.f) ? o : (__expf(o) - 1.f);  // ELU

    // fused gemm2 + scores2 (row-local; R9-validated)
    arow[l] = a1v;
    __syncthreads();
    const int cc = l & 15;
    const int kg = l >> 4;
    float hacc = 0.f;
    #pragma unroll
    for (int k = 0; k < 16; ++k)
        hacc += arow[kg * 16 + k] * W2[(kg * 16 + k) * C2 + cc];
    hacc += __shfl_xor(hacc, 16);
    hacc += __shfl_xor(hacc, 32);
    if (l < C2) h2[(size_t)i * C2 + l] = hacc;
    float s2 = hacc * a2s[cc];
    float d2 = hacc * a2d[cc];
    s2 += __shfl_xor(s2, 1); s2 += __shfl_xor(s2, 2);
    s2 += __shfl_xor(s2, 4); s2 += __shfl_xor(s2, 8);
    d2 += __shfl_xor(d2, 1); d2 += __shfl_xor(d2, 2);
    d2 += __shfl_xor(d2, 4); d2 += __shfl_xor(d2, 8);
    if (l == 0) { es2[i] = s2; ed2[i] = d2; }
}

// ---------------------------------------------------------------------------
// Attention layer 2. R9 mega-kernel phase E (validated) as standalone:
// 4 waves/block, per-wave LDS slices, fixed 2-trip loop. 1024 blocks.
// ---------------------------------------------------------------------------
__global__ __launch_bounds__(256) void attn2_kernel(
        const unsigned short* __restrict__ neigh, const int* __restrict__ deg,
        const float* __restrict__ h2, const float* __restrict__ es2,
        const float* __restrict__ ed2, float* __restrict__ out) {
    __shared__ unsigned short listA[4 * MAXDEG];
    __shared__ float pbufA[4 * 64];
    const int t = threadIdx.x;
    const int wv = t >> 6;
    const int l = t & 63;
    const int i = blockIdx.x * 4 + wv;
    unsigned short* list = listA + wv * MAXDEG;
    float* pb = pbufA + wv * 64;
    const int c = l & 15;
    const int g = l >> 4;

    const int K = deg[i];
    const unsigned short* lst = neigh + (size_t)i * MAXDEG;
    for (int j = l; j < MAXDEG; j += 64) list[j] = (j < K) ? lst[j] : (unsigned short)0;
    __syncthreads();

    float m = -1e30f, lsum = 0.f, acc = 0.f;
    const float esi = es2[i];
    for (int t0 = 0; t0 < MAXDEG; t0 += 64) {    // fixed 2 trips
        const int tc = min(64, K - t0);
        if (tc > 0) {
            const bool valid = l < tc;
            const int j = valid ? (int)list[t0 + l] : 0;
            float v = esi + ed2[j];
            v = (v >= 0.f) ? v : 0.2f * v;
            float s = valid ? v : -1e30f;
            float tm = wave_max(s);
            float mnew = fmaxf(m, tm);
            float p = valid ? __expf(s - mnew) : 0.f;
            float ts = wave_sum(p);
            float alpha = __expf(m - mnew);
            lsum = lsum * alpha + ts;
            m = mnew;
            pb[l] = p;
            acc *= alpha;
        }
        __syncthreads();             // uniform
        if (tc > 0) {
            const int tcPad = (tc + 3) & ~3;
            for (int u = g; u < tcPad; u += 4) {
                int jn = (int)list[t0 + u];
                acc += pb[u] * h2[(size_t)jn * C2 + c];
            }
        }
        __syncthreads();             // uniform
    }
    acc += __shfl_xor(acc, 16);
    acc += __shfl_xor(acc, 32);
    if (l < C2) out[(size_t)i * C2 + l] = acc / lsum;
}

extern "C" void kernel_launch(void* const* d_in, const int* in_sizes, int n_in,
                              void* d_out, int out_size, void* d_ws, size_t ws_size,
                              hipStream_t stream) {
    const float* x           = (const float*)d_in[0];
    const unsigned char* adj = (const unsigned char*)d_in[1];
    const float* W1          = (const float*)d_in[2];
    const float* a1src       = (const float*)d_in[3];
    const float* a1dst       = (const float*)d_in[4];
    const float* W2          = (const float*)d_in[5];
    const float* a2src       = (const float*)d_in[6];
    const float* a2dst       = (const float*)d_in[7];
    float* out = (float*)d_out;

    // workspace layout (~2.6 MB), all offsets 256B-aligned
    char* ws = (char*)d_ws;
    size_t off = 0;
    int* flag = (int*)(ws + off);                 off += 256;
    unsigned short* neigh = (unsigned short*)(ws + off);
    off += (size_t)N_NODES * MAXDEG * 2;          // 1 MB
    int* deg = (int*)(ws + off);                  off += (size_t)N_NODES * 4;
    float* h1 = (float*)(ws + off);               off += (size_t)N_NODES * F1 * 4;
    float* es1 = (float*)(ws + off);              off += (size_t)N_NODES * NH1 * 4;
    float* ed1 = (float*)(ws + off);              off += (size_t)N_NODES * NH1 * 4;
    float* h2 = (float*)(ws + off);               off += (size_t)N_NODES * C2 * 4;
    float* es2 = (float*)(ws + off);              off += (size_t)N_NODES * 4;
    float* ed2 = (float*)(ws + off);              off += (size_t)N_NODES * 4;

    hipLaunchKernelGGL(detect_width_kernel, dim3(1), dim3(256), 0, stream, adj, flag);
    hipLaunchKernelGGL(frontend_kernel, dim3(N_NODES + N_NODES / 4), dim3(256), 0, stream,
                       adj, flag, neigh, deg, x, W1, a1src, a1dst, h1, es1, ed1);
    hipLaunchKernelGGL(attn1_kernel, dim3(N_NODES / 4), dim3(256), 0, stream,
                       neigh, deg, h1, es1, ed1, W2, a2src, a2dst, h2, es2, ed2);
    hipLaunchKernelGGL(attn2_kernel, dim3(N_NODES / 4), dim3(256), 0, stream,
                       neigh, deg, h2, es2, ed2, out);
}